// Round 1
// baseline (47.189 us; speedup 1.0000x reference)
//
#include <hip/hip_runtime.h>
#include <math.h>

#define ROWS 1000000
#define K2_BLOCKS 1024
#define K2_THREADS 256

// ---------------------------------------------------------------------------
// K1: entire tiny front-end in one block.
//   - 3 embedding chains (2x ResNet16 + Linear 16->5)
//   - LayerNorm(15)
//   - ODE: Linear(5->32) + ResNet32 ; h = hidden + ode
//   - GRU step -> h_new
//   - heads fc5/fc6 (24-wide log_softmax) and h_new written to d_out
//   - h_new written to ws[0:32] for the big head kernel
// ---------------------------------------------------------------------------
__global__ __launch_bounds__(128) void front_kernel(
    const int* __restrict__ x, const float* __restrict__ hidden, const int* __restrict__ pos,
    const float* __restrict__ loc_emb, const float* __restrict__ arr_emb,
    const float* __restrict__ dur_emb, const float* __restrict__ pos_emb,
    const float* __restrict__ f1rW1, const float* __restrict__ f1rb1,
    const float* __restrict__ f1rW2, const float* __restrict__ f1rb2,
    const float* __restrict__ f1W,   const float* __restrict__ f1b,
    const float* __restrict__ f2rW1, const float* __restrict__ f2rb1,
    const float* __restrict__ f2rW2, const float* __restrict__ f2rb2,
    const float* __restrict__ f2W,   const float* __restrict__ f2b,
    const float* __restrict__ f3rW1, const float* __restrict__ f3rb1,
    const float* __restrict__ f3rW2, const float* __restrict__ f3rb2,
    const float* __restrict__ f3W,   const float* __restrict__ f3b,
    const float* __restrict__ ln_g,  const float* __restrict__ ln_b,
    const float* __restrict__ ode_W, const float* __restrict__ ode_b,
    const float* __restrict__ oW1,   const float* __restrict__ ob1,
    const float* __restrict__ oW2,   const float* __restrict__ ob2,
    const float* __restrict__ fc5_W, const float* __restrict__ fc5_b,
    const float* __restrict__ fc6_W, const float* __restrict__ fc6_b,
    const float* __restrict__ gWih,  const float* __restrict__ gbih,
    const float* __restrict__ gWhh,  const float* __restrict__ gbhh,
    float* __restrict__ out, float* __restrict__ ws)
{
    __shared__ float e[3][16];      // chain state
    __shared__ float tr[3][16];     // relu temp
    __shared__ float h1[3][16];     // mid temp
    __shared__ float praw[15];      // concat(loc,arr,dur) pre-layernorm
    __shared__ float pnorm[15];     // after layernorm
    __shared__ float ode0[32], odt[32], hvec[32], hnew[32], pe[32];
    __shared__ float gi[96], gh[96];
    __shared__ float a5[24], a6[24];
    __shared__ float red[4];

    const int t = threadIdx.x;

    // --- load embeddings + pos_e ---
    if (t < 48) {
        int c = t >> 4, j = t & 15;
        const float* emb = (c == 0) ? (loc_emb + (size_t)x[0] * 16)
                         : (c == 1) ? (arr_emb + (size_t)x[1] * 16)
                                    : (dur_emb + (size_t)x[2] * 16);
        e[c][j] = emb[j];
    }
    if (t < 32) pe[t] = pos_emb[pos[0] * 32 + t];
    __syncthreads();

    // --- two ResNet16 blocks per chain ---
    for (int i = 0; i < 2; ++i) {
        if (t < 48) { int c = t >> 4, j = t & 15; tr[c][j] = fmaxf(e[c][j], 0.f); }
        __syncthreads();
        if (t < 48) {
            int c = t >> 4, j = t & 15;
            const float* W1 = ((c == 0) ? f1rW1 : (c == 1) ? f2rW1 : f3rW1) + i * 256 + j * 16;
            const float* b1 = ((c == 0) ? f1rb1 : (c == 1) ? f2rb1 : f3rb1) + i * 16;
            float a = b1[j];
            #pragma unroll
            for (int k = 0; k < 16; ++k) a += W1[k] * tr[c][k];
            h1[c][j] = fmaxf(a, 0.f);
        }
        __syncthreads();
        if (t < 48) {
            int c = t >> 4, j = t & 15;
            const float* W2 = ((c == 0) ? f1rW2 : (c == 1) ? f2rW2 : f3rW2) + i * 256 + j * 16;
            const float* b2 = ((c == 0) ? f1rb2 : (c == 1) ? f2rb2 : f3rb2) + i * 16;
            float a = b2[j];
            #pragma unroll
            for (int k = 0; k < 16; ++k) a += W2[k] * h1[c][k];
            e[c][j] += 0.3f * a;
        }
        __syncthreads();
    }

    // --- final Linear 16->5 per chain -> praw[15] ---
    if (t < 15) {
        int c = t / 5, q = t % 5;
        const float* W = ((c == 0) ? f1W : (c == 1) ? f2W : f3W) + q * 16;
        const float* b = ((c == 0) ? f1b : (c == 1) ? f2b : f3b);
        float a = b[q];
        #pragma unroll
        for (int k = 0; k < 16; ++k) a += W[k] * e[c][k];
        praw[t] = a;
    }
    __syncthreads();

    // --- LayerNorm(15) ---
    if (t == 0) {
        float mu = 0.f;
        for (int k = 0; k < 15; ++k) mu += praw[k];
        mu *= (1.f / 15.f);
        float var = 0.f;
        for (int k = 0; k < 15; ++k) { float d = praw[k] - mu; var += d * d; }
        var *= (1.f / 15.f);
        red[0] = mu;
        red[1] = rsqrtf(var + 1e-5f);
    }
    __syncthreads();
    if (t < 15) pnorm[t] = (praw[t] - red[0]) * red[1] * ln_g[t] + ln_b[t];

    // --- ODE: Linear(5->32) on raw dur (praw[10..14]) ---
    if (t < 32) {
        float a = ode_b[t];
        const float* W = ode_W + t * 5;
        #pragma unroll
        for (int k = 0; k < 5; ++k) a += W[k] * praw[10 + k];
        ode0[t] = a;
    }
    __syncthreads();
    if (t < 32) {
        float a = ob1[t];
        const float* W = oW1 + t * 32;
        #pragma unroll
        for (int k = 0; k < 32; ++k) a += W[k] * fmaxf(ode0[k], 0.f);
        odt[t] = fmaxf(a, 0.f);
    }
    __syncthreads();
    if (t < 32) {
        float a = ob2[t];
        const float* W = oW2 + t * 32;
        #pragma unroll
        for (int k = 0; k < 32; ++k) a += W[k] * odt[k];
        hvec[t] = hidden[t] + ode0[t] + 0.3f * a;   // h = hidden + resnet(ode0)
    }
    __syncthreads();

    // --- GRU: gi = Wih@pnorm + bih ; gh = Whh@hvec + bhh ---
    if (t < 96) {
        float a = gbih[t];
        const float* W = gWih + t * 15;
        #pragma unroll
        for (int k = 0; k < 15; ++k) a += W[k] * pnorm[k];
        gi[t] = a;
        float c2 = gbhh[t];
        const float* V = gWhh + t * 32;
        #pragma unroll
        for (int k = 0; k < 32; ++k) c2 += V[k] * hvec[k];
        gh[t] = c2;
    }
    __syncthreads();
    if (t < 32) {
        float r = 1.f / (1.f + expf(-(gi[t] + gh[t])));
        float z = 1.f / (1.f + expf(-(gi[32 + t] + gh[32 + t])));
        float n = tanhf(gi[64 + t] + r * gh[64 + t]);
        float hn = (1.f - z) * n + z * hvec[t];
        hnew[t] = hn;
        ws[t] = hn;                       // for the fc4 kernel
        out[ROWS + 48 + t] = hn;          // h_new output
    }
    __syncthreads();

    // --- heads fc5 (h_new + pos_e) and fc6 (h_new), 24-wide ---
    if (t < 24) {
        float a = fc5_b[t];
        const float* W = fc5_W + t * 32;
        #pragma unroll
        for (int k = 0; k < 32; ++k) a += W[k] * (hnew[k] + pe[k]);
        a5[t] = a;
        float b = fc6_b[t];
        const float* V = fc6_W + t * 32;
        #pragma unroll
        for (int k = 0; k < 32; ++k) b += V[k] * hnew[k];
        a6[t] = b;
    }
    __syncthreads();
    if (t == 0) {
        float m = -INFINITY;
        for (int k = 0; k < 24; ++k) m = fmaxf(m, a5[k]);
        float s = 0.f;
        for (int k = 0; k < 24; ++k) s += expf(a5[k] - m);
        red[2] = m + logf(s);
        m = -INFINITY;
        for (int k = 0; k < 24; ++k) m = fmaxf(m, a6[k]);
        s = 0.f;
        for (int k = 0; k < 24; ++k) s += expf(a6[k] - m);
        red[3] = m + logf(s);
    }
    __syncthreads();
    if (t < 24) {
        out[ROWS + t]      = a5[t] - red[2];
        out[ROWS + 24 + t] = a6[t] - red[3];
    }
}

// ---------------------------------------------------------------------------
// K2: logits for next_loc. Each thread: dot(h, fc4_W[r]) + b[r] via float4.
// Writes unnormalized logits to out[0:ROWS); per-block online (max, sumexp)
// partials written to ws.
// ---------------------------------------------------------------------------
__global__ __launch_bounds__(K2_THREADS) void logits_kernel(
    const float* __restrict__ W, const float* __restrict__ b,
    const float* __restrict__ ws_h, float* __restrict__ out,
    float* __restrict__ partials)
{
    __shared__ float hs[32];
    if (threadIdx.x < 32) hs[threadIdx.x] = ws_h[threadIdx.x];
    __syncthreads();

    float hr[32];
    #pragma unroll
    for (int k = 0; k < 32; ++k) hr[k] = hs[k];

    const float4* W4 = (const float4*)W;
    float m = -INFINITY, s = 0.f;

    for (int r = blockIdx.x * K2_THREADS + threadIdx.x; r < ROWS;
         r += K2_BLOCKS * K2_THREADS) {
        float acc = b[r];
        #pragma unroll
        for (int j = 0; j < 8; ++j) {
            float4 w = W4[(size_t)r * 8 + j];
            acc += w.x * hr[4 * j] + w.y * hr[4 * j + 1]
                 + w.z * hr[4 * j + 2] + w.w * hr[4 * j + 3];
        }
        out[r] = acc;
        // online (max, sum-exp); every thread gets >=3 rows so m is finite
        if (acc > m) { s = s * expf(m - acc) + 1.f; m = acc; }
        else         { s += expf(acc - m); }
    }

    __shared__ float sm[K2_THREADS], ss[K2_THREADS];
    sm[threadIdx.x] = m; ss[threadIdx.x] = s;
    __syncthreads();
    for (int off = K2_THREADS / 2; off > 0; off >>= 1) {
        if (threadIdx.x < off) {
            float m2 = sm[threadIdx.x + off], s2 = ss[threadIdx.x + off];
            float M  = fmaxf(sm[threadIdx.x], m2);
            ss[threadIdx.x] = ss[threadIdx.x] * expf(sm[threadIdx.x] - M)
                            + s2 * expf(m2 - M);
            sm[threadIdx.x] = M;
        }
        __syncthreads();
    }
    if (threadIdx.x == 0) {
        partials[2 * blockIdx.x]     = sm[0];
        partials[2 * blockIdx.x + 1] = ss[0];
    }
}

// ---------------------------------------------------------------------------
// K3: reduce K2_BLOCKS partial (max, sumexp) pairs -> lse scalar in ws.
// ---------------------------------------------------------------------------
__global__ __launch_bounds__(256) void lse_reduce_kernel(
    const float* __restrict__ partials, float* __restrict__ lse)
{
    __shared__ float sm[256], ss[256];
    const int t = threadIdx.x;
    float m = -INFINITY, s = 0.f;
    for (int i = t; i < K2_BLOCKS; i += 256) {
        float m2 = partials[2 * i], s2 = partials[2 * i + 1];
        float M = fmaxf(m, m2);
        s = s * ((m == -INFINITY) ? 0.f : expf(m - M)) + s2 * expf(m2 - M);
        m = M;
    }
    sm[t] = m; ss[t] = s;
    __syncthreads();
    for (int off = 128; off > 0; off >>= 1) {
        if (t < off) {
            float m2 = sm[t + off], s2 = ss[t + off];
            float M = fmaxf(sm[t], m2);
            ss[t] = ss[t] * expf(sm[t] - M) + s2 * expf(m2 - M);
            sm[t] = M;
        }
        __syncthreads();
    }
    if (t == 0) lse[0] = sm[0] + logf(ss[0]);
}

// ---------------------------------------------------------------------------
// K4: out[r] -= lse  (float4 over the 1M logits)
// ---------------------------------------------------------------------------
__global__ __launch_bounds__(256) void finalize_kernel(
    float* __restrict__ out, const float* __restrict__ lse)
{
    const int r4 = blockIdx.x * 256 + threadIdx.x;
    if (r4 < ROWS / 4) {
        const float l = lse[0];
        float4* o4 = (float4*)out;
        float4 v = o4[r4];
        v.x -= l; v.y -= l; v.z -= l; v.w -= l;
        o4[r4] = v;
    }
}

extern "C" void kernel_launch(void* const* d_in, const int* in_sizes, int n_in,
                              void* d_out, int out_size, void* d_ws, size_t ws_size,
                              hipStream_t stream) {
    const int*   x       = (const int*)  d_in[0];
    const float* hidden  = (const float*)d_in[1];
    const int*   pos     = (const int*)  d_in[2];
    const float* loc_emb = (const float*)d_in[3];
    const float* arr_emb = (const float*)d_in[4];
    const float* dur_emb = (const float*)d_in[5];
    const float* pos_emb = (const float*)d_in[6];
    const float* f1rW1 = (const float*)d_in[7];
    const float* f1rb1 = (const float*)d_in[8];
    const float* f1rW2 = (const float*)d_in[9];
    const float* f1rb2 = (const float*)d_in[10];
    const float* f1W   = (const float*)d_in[11];
    const float* f1b   = (const float*)d_in[12];
    const float* f2rW1 = (const float*)d_in[13];
    const float* f2rb1 = (const float*)d_in[14];
    const float* f2rW2 = (const float*)d_in[15];
    const float* f2rb2 = (const float*)d_in[16];
    const float* f2W   = (const float*)d_in[17];
    const float* f2b   = (const float*)d_in[18];
    const float* f3rW1 = (const float*)d_in[19];
    const float* f3rb1 = (const float*)d_in[20];
    const float* f3rW2 = (const float*)d_in[21];
    const float* f3rb2 = (const float*)d_in[22];
    const float* f3W   = (const float*)d_in[23];
    const float* f3b   = (const float*)d_in[24];
    const float* ln_g  = (const float*)d_in[25];
    const float* ln_b  = (const float*)d_in[26];
    const float* ode_W = (const float*)d_in[27];
    const float* ode_b = (const float*)d_in[28];
    const float* oW1   = (const float*)d_in[29];
    const float* ob1   = (const float*)d_in[30];
    const float* oW2   = (const float*)d_in[31];
    const float* ob2   = (const float*)d_in[32];
    const float* fc4_W = (const float*)d_in[33];
    const float* fc4_b = (const float*)d_in[34];
    const float* fc5_W = (const float*)d_in[35];
    const float* fc5_b = (const float*)d_in[36];
    const float* fc6_W = (const float*)d_in[37];
    const float* fc6_b = (const float*)d_in[38];
    const float* gWih  = (const float*)d_in[39];
    const float* gbih  = (const float*)d_in[40];
    const float* gWhh  = (const float*)d_in[41];
    const float* gbhh  = (const float*)d_in[42];

    float* out = (float*)d_out;
    float* wsf = (float*)d_ws;
    // ws layout: [0:32) h_new, [32] lse, [64 : 64+2*K2_BLOCKS) partials
    float* ws_h        = wsf;
    float* ws_lse      = wsf + 32;
    float* ws_partials = wsf + 64;

    front_kernel<<<1, 128, 0, stream>>>(
        x, hidden, pos, loc_emb, arr_emb, dur_emb, pos_emb,
        f1rW1, f1rb1, f1rW2, f1rb2, f1W, f1b,
        f2rW1, f2rb1, f2rW2, f2rb2, f2W, f2b,
        f3rW1, f3rb1, f3rW2, f3rb2, f3W, f3b,
        ln_g, ln_b, ode_W, ode_b, oW1, ob1, oW2, ob2,
        fc5_W, fc5_b, fc6_W, fc6_b, gWih, gbih, gWhh, gbhh,
        out, ws_h);

    logits_kernel<<<K2_BLOCKS, K2_THREADS, 0, stream>>>(
        fc4_W, fc4_b, ws_h, out, ws_partials);

    lse_reduce_kernel<<<1, 256, 0, stream>>>(ws_partials, ws_lse);

    finalize_kernel<<<(ROWS / 4 + 255) / 256, 256, 0, stream>>>(out, ws_lse);
}